// Round 5
// baseline (255.758 us; speedup 1.0000x reference)
//
#include <hip/hip_runtime.h>

#define N_NODES 50000
#define N_EDGES 800000
#define IN_DIM 128
#define HID 64
#define NT 32        // nodes per block in gin layer
#define RST_PITCH 68 // 272B rows: 16B-aligned, conflict-free broadcasts

using v4f = __attribute__((ext_vector_type(4))) float;

// ---------------- CSR build ----------------
// 1 edge/thread: 3125 blocks -> 32 waves/CU, max atomic chains in flight.

__global__ void deg_kernel(const int* __restrict__ dst, int* __restrict__ deg, int nE) {
    int i = blockIdx.x * blockDim.x + threadIdx.x;
    if (i < nE) atomicAdd(&deg[dst[i]], 1);
}

__global__ void scan1_kernel(const int* __restrict__ deg, int* __restrict__ row_ptr,
                             int* __restrict__ blksum, int n) {
    __shared__ int sh[256];
    int t = threadIdx.x;
    int i = blockIdx.x * 256 + t;
    int v = (i < n) ? deg[i] : 0;
    sh[t] = v;
    __syncthreads();
    for (int off = 1; off < 256; off <<= 1) {
        int add = (t >= off) ? sh[t - off] : 0;
        __syncthreads();
        sh[t] += add;
        __syncthreads();
    }
    int incl = sh[t];
    if (i < n) row_ptr[i] = incl - v;
    if (t == 255) blksum[blockIdx.x] = incl;
}

// one-block exclusive scan of block sums; also zeroes row n of hA/hB
__global__ void scan2_kernel(int* __restrict__ blksum, int nblk,
                             float* __restrict__ hA, float* __restrict__ hB) {
    __shared__ int sh[256];
    int t = threadIdx.x;
    if (t < HID) {
        hA[(size_t)N_NODES * HID + t] = 0.f;
        hB[(size_t)N_NODES * HID + t] = 0.f;
    }
    int v = (t < nblk) ? blksum[t] : 0;
    sh[t] = v;
    __syncthreads();
    for (int off = 1; off < 256; off <<= 1) {
        int add = (t >= off) ? sh[t - off] : 0;
        __syncthreads();
        sh[t] += add;
        __syncthreads();
    }
    if (t < nblk) blksum[t] = sh[t] - v;
}

__global__ void scan3_kernel(int* __restrict__ row_ptr, const int* __restrict__ blksum,
                             int* __restrict__ cursor, int n, int nE) {
    int i = blockIdx.x * 256 + threadIdx.x;
    if (i < n) {
        int r = row_ptr[i] + blksum[i >> 8];
        row_ptr[i] = r;
        cursor[i] = r;
    }
    if (i == 0) row_ptr[n] = nE;
}

__global__ void fill_kernel(const int* __restrict__ src, const int* __restrict__ dst,
                            int* __restrict__ cursor, int* __restrict__ col, int nE) {
    int i = blockIdx.x * blockDim.x + threadIdx.x;
    if (i < nE) {
        int p = atomicAdd(&cursor[dst[i]], 1);
        col[p] = src[i];
    }
}

// ---------------- fc_init: h0 = relu(features @ fc_w + fc_b) ----------------

#define FT_PITCH 132
#define FCNT 64

__global__ __launch_bounds__(256) void fc_init_kernel(
        const float* __restrict__ feat, const float* __restrict__ W,
        const float* __restrict__ bias, float* __restrict__ h, int n) {
    __shared__ float Wl[IN_DIM * HID];      // 32 KB
    __shared__ float ft[FCNT * FT_PITCH];   // 33 KB

    int base = blockIdx.x * FCNT;
    for (int i = threadIdx.x; i < IN_DIM * HID / 4; i += 256)
        *reinterpret_cast<v4f*>(&Wl[i * 4]) = *reinterpret_cast<const v4f*>(&W[i * 4]);
    {
        int f4 = threadIdx.x & 31;
        int r0 = threadIdx.x >> 5;
        for (int p = 0; p < 8; ++p) {
            int r = p * 8 + r0;
            int node = base + r;
            v4f v = {0.f, 0.f, 0.f, 0.f};
            if (node < n) v = *reinterpret_cast<const v4f*>(&feat[(size_t)node * IN_DIM + f4 * 4]);
            *reinterpret_cast<v4f*>(&ft[r * FT_PITCH + f4 * 4]) = v;
        }
    }
    __syncthreads();

    int tx = threadIdx.x & 15;
    int ty = threadIdx.x >> 4;
    v4f acc[4];
    v4f b4 = *reinterpret_cast<const v4f*>(&bias[tx * 4]);
    acc[0] = b4; acc[1] = b4; acc[2] = b4; acc[3] = b4;

#pragma unroll 16
    for (int k = 0; k < IN_DIM; ++k) {
        v4f w4 = *reinterpret_cast<const v4f*>(&Wl[k * HID + tx * 4]);
        float a0 = ft[(ty * 4 + 0) * FT_PITCH + k];
        float a1 = ft[(ty * 4 + 1) * FT_PITCH + k];
        float a2 = ft[(ty * 4 + 2) * FT_PITCH + k];
        float a3 = ft[(ty * 4 + 3) * FT_PITCH + k];
        acc[0] += a0 * w4;
        acc[1] += a1 * w4;
        acc[2] += a2 * w4;
        acc[3] += a3 * w4;
    }
#pragma unroll
    for (int i = 0; i < 4; ++i) {
        int node = base + ty * 4 + i;
        if (node < n) {
            v4f o;
            o[0] = fmaxf(acc[i][0], 0.f);
            o[1] = fmaxf(acc[i][1], 0.f);
            o[2] = fmaxf(acc[i][2], 0.f);
            o[3] = fmaxf(acc[i][3], 0.f);
            *reinterpret_cast<v4f*>(&h[(size_t)node * HID + tx * 4]) = o;
        }
    }
}

// ---------------- fused GIN layer (512 threads, NT=32) ----------------
// Phase A: each wave gathers 4 nodes with their first 64-edge chunks
// INTERLEAVED in one j-loop -> up to 16 independent 1KB gathers in flight.
// Tail lanes of myc hold index n (zero row), so an overshoot idx >= cnt
// fetches zeros: no bounds check, no divergence, convergent shfl.
// Phase B: 32x64x64 GEMM, 1 node x 4 outputs per thread, W in LDS.

__global__ __launch_bounds__(512) void gin_layer_kernel(
        const float* __restrict__ h_in, const int* __restrict__ row_ptr,
        const int* __restrict__ col, const float* __restrict__ W,
        const float* __restrict__ bias, const float* __restrict__ eps_arr, int layer,
        float* __restrict__ h_out, int n) {
    __shared__ float Wl[HID * HID];         // 16 KB
    __shared__ float rst[NT * RST_PITCH];   // 8.7 KB

    for (int i = threadIdx.x; i < HID * HID / 4; i += 512)
        *reinterpret_cast<v4f*>(&Wl[i * 4]) = *reinterpret_cast<const v4f*>(&W[i * 4]);

    int wid = threadIdx.x >> 6, lane = threadIdx.x & 63;
    int g = lane >> 4;          // edge subgroup 0..3
    int fo = (lane & 15) * 4;   // feature quad offset
    int base = blockIdx.x * NT;
    int node0 = base + wid * 4;
    float eps1 = 1.f + eps_arr[layer];

    int s0[4], dg[4], myc[4];
    v4f acc[4];
    int jmax = 0;
#pragma unroll
    for (int i = 0; i < 4; ++i) {
        int node = node0 + i;
        int a = 0, b = 0;
        if (node < n) { a = row_ptr[node]; b = row_ptr[node + 1]; }
        s0[i] = a;
        dg[i] = b - a;
        int c = b - a; if (c > 64) c = 64;
        myc[i] = (lane < c) ? col[a + lane] : n;   // pad -> zero row
        int jm = (c + 3) >> 2;
        if (jm > jmax) jmax = jm;
        acc[i] = (v4f){0.f, 0.f, 0.f, 0.f};
    }
    // interleaved first chunks: 4 independent loads per j
    for (int j = 0; j < jmax; ++j) {
        int idx = j * 4 + g;
#pragma unroll
        for (int i = 0; i < 4; ++i) {
            int sn = __shfl(myc[i], idx);          // convergent; pad reads row n
            acc[i] += *reinterpret_cast<const v4f*>(&h_in[(size_t)sn * HID + fo]);
        }
    }
    // remainder chunks (degree > 64) — rare
#pragma unroll
    for (int i = 0; i < 4; ++i) {
        for (int e0 = s0[i] + 64; e0 < s0[i] + dg[i]; e0 += 64) {
            int c = s0[i] + dg[i] - e0; if (c > 64) c = 64;
            int m = (lane < c) ? col[e0 + lane] : n;
            int jm = (c + 3) >> 2;
            for (int j = 0; j < jm; ++j) {
                int sn = __shfl(m, j * 4 + g);
                acc[i] += *reinterpret_cast<const v4f*>(&h_in[(size_t)sn * HID + fo]);
            }
        }
    }
#pragma unroll
    for (int i = 0; i < 4; ++i) {
#pragma unroll
        for (int c = 0; c < 4; ++c) {
            acc[i][c] += __shfl_xor(acc[i][c], 16);
            acc[i][c] += __shfl_xor(acc[i][c], 32);
        }
        int node = node0 + i;
        float sc = (dg[i] > 0) ? 1.f / (float)dg[i] : 0.f;
        if (node < n && lane < 16) {
            v4f self = *reinterpret_cast<const v4f*>(&h_in[(size_t)node * HID + fo]);
            v4f rv = eps1 * self + acc[i] * sc;
            *reinterpret_cast<v4f*>(&rst[(wid * 4 + i) * RST_PITCH + fo]) = rv;
        }
    }
    __syncthreads();

    // phase B: out = relu(rst @ W + b); 1 node x 4 outputs per thread
    int tx = threadIdx.x & 15;   // output quad
    int ty = threadIdx.x >> 4;   // node 0..31
    v4f a4 = *reinterpret_cast<const v4f*>(&bias[tx * 4]);
#pragma unroll 16
    for (int k = 0; k < HID; ++k) {
        v4f w4 = *reinterpret_cast<const v4f*>(&Wl[k * HID + tx * 4]);
        a4 += rst[ty * RST_PITCH + k] * w4;
    }
    int node = base + ty;
    if (node < n) {
        v4f o;
        o[0] = fmaxf(a4[0], 0.f); o[1] = fmaxf(a4[1], 0.f);
        o[2] = fmaxf(a4[2], 0.f); o[3] = fmaxf(a4[3], 0.f);
        *reinterpret_cast<v4f*>(&h_out[(size_t)node * HID + tx * 4]) = o;
    }
}

// ---------------- launch ----------------

extern "C" void kernel_launch(void* const* d_in, const int* in_sizes, int n_in,
                              void* d_out, int out_size, void* d_ws, size_t ws_size,
                              hipStream_t stream) {
    const float* feat = (const float*)d_in[0];
    const int*   src  = (const int*)d_in[1];
    const int*   dst  = (const int*)d_in[2];
    const float* fc_w = (const float*)d_in[3];
    const float* fc_b = (const float*)d_in[4];
    const float* w0   = (const float*)d_in[5];
    const float* b0   = (const float*)d_in[6];
    const float* w1   = (const float*)d_in[7];
    const float* b1   = (const float*)d_in[8];
    const float* w2   = (const float*)d_in[9];
    const float* b2   = (const float*)d_in[10];
    const float* eps  = (const float*)d_in[11];
    float* out = (float*)d_out;

    char* ws = (char*)d_ws;
    size_t off = 0;
    auto alloc = [&](size_t bytes) {
        size_t o = off;
        off += (bytes + 255) & ~(size_t)255;
        return (void*)(ws + o);
    };
    int*   deg     = (int*)alloc((size_t)N_NODES * 4);
    int*   row_ptr = (int*)alloc((size_t)(N_NODES + 1) * 4);
    int*   cursor  = (int*)alloc((size_t)N_NODES * 4);
    int*   blksum  = (int*)alloc(256 * 4);
    int*   col     = (int*)alloc((size_t)N_EDGES * 4);
    float* hA      = (float*)alloc((size_t)(N_NODES + 1) * HID * 4);
    float* hB      = (float*)alloc((size_t)(N_NODES + 1) * HID * 4);

    const int nblkN = (N_NODES + 255) / 256;       // 196
    const int nblkE = (N_EDGES + 255) / 256;       // 3125

    hipMemsetAsync(deg, 0, (size_t)N_NODES * 4, stream);
    deg_kernel<<<nblkE, 256, 0, stream>>>(dst, deg, N_EDGES);
    scan1_kernel<<<nblkN, 256, 0, stream>>>(deg, row_ptr, blksum, N_NODES);
    scan2_kernel<<<1, 256, 0, stream>>>(blksum, nblkN, hA, hB);
    scan3_kernel<<<nblkN, 256, 0, stream>>>(row_ptr, blksum, cursor, N_NODES, N_EDGES);
    fill_kernel<<<nblkE, 256, 0, stream>>>(src, dst, cursor, col, N_EDGES);

    const int fcBlocks = (N_NODES + FCNT - 1) / FCNT;   // 782
    fc_init_kernel<<<fcBlocks, 256, 0, stream>>>(feat, fc_w, fc_b, hA, N_NODES);
    const int ginBlocks = (N_NODES + NT - 1) / NT;      // 1563
    gin_layer_kernel<<<ginBlocks, 512, 0, stream>>>(hA, row_ptr, col, w0, b0, eps, 0, hB, N_NODES);
    gin_layer_kernel<<<ginBlocks, 512, 0, stream>>>(hB, row_ptr, col, w1, b1, eps, 1, hA, N_NODES);
    gin_layer_kernel<<<ginBlocks, 512, 0, stream>>>(hA, row_ptr, col, w2, b2, eps, 2, out, N_NODES);
}

// Round 6
// 224.723 us; speedup vs baseline: 1.1381x; 1.1381x over previous
//
#include <hip/hip_runtime.h>

#define N_NODES 50000
#define N_EDGES 800000
#define IN_DIM 128
#define HID 64
#define NT 64        // nodes per block in gin layer
#define RST_PITCH 68 // 272B rows: 16B-aligned, conflict-free broadcasts
#define NXCD 8
#define NODES_PER_RANGE (N_NODES / NXCD)   // 6250

using v4f = __attribute__((ext_vector_type(4))) float;

// ---------------- CSR build ----------------
// deg/fill use an XCD-affine dst-range sweep: block's range = blockIdx.x & 7
// (blockIdx -> XCD is round-robin %8 on MI355X). Each XCD's atomics and col
// scatter-writes then stay in its own L2 segment (cursor 25KB, col ~400KB),
// killing the 16x line-eviction write amplification (51.6MB -> ~3.2MB HBM).
// Price: 8x redundant edge reads (51MB ~ 10us). Correctness does not depend
// on the blockIdx->XCD mapping.

__global__ __launch_bounds__(256) void deg_sweep_kernel(
        const int* __restrict__ dst, int* __restrict__ deg) {
    int r = blockIdx.x & (NXCD - 1);
    int lo = r * NODES_PER_RANGE, hi = lo + NODES_PER_RANGE;
    int nch = gridDim.x >> 3;
    int cb = blockIdx.x >> 3;
    int stride = nch * blockDim.x;
    for (int t = cb * blockDim.x + threadIdx.x; t < N_EDGES / 4; t += stride) {
        int4 d4 = reinterpret_cast<const int4*>(dst)[t];
        if (d4.x >= lo && d4.x < hi) atomicAdd(&deg[d4.x], 1);
        if (d4.y >= lo && d4.y < hi) atomicAdd(&deg[d4.y], 1);
        if (d4.z >= lo && d4.z < hi) atomicAdd(&deg[d4.z], 1);
        if (d4.w >= lo && d4.w < hi) atomicAdd(&deg[d4.w], 1);
    }
}

__global__ __launch_bounds__(256) void fill_sweep_kernel(
        const int* __restrict__ src, const int* __restrict__ dst,
        int* __restrict__ cursor, int* __restrict__ col) {
    int r = blockIdx.x & (NXCD - 1);
    int lo = r * NODES_PER_RANGE, hi = lo + NODES_PER_RANGE;
    int nch = gridDim.x >> 3;
    int cb = blockIdx.x >> 3;
    int stride = nch * blockDim.x;
    for (int t = cb * blockDim.x + threadIdx.x; t < N_EDGES / 4; t += stride) {
        int4 d4 = reinterpret_cast<const int4*>(dst)[t];
        int4 s4 = reinterpret_cast<const int4*>(src)[t];
        if (d4.x >= lo && d4.x < hi) col[atomicAdd(&cursor[d4.x], 1)] = s4.x;
        if (d4.y >= lo && d4.y < hi) col[atomicAdd(&cursor[d4.y], 1)] = s4.y;
        if (d4.z >= lo && d4.z < hi) col[atomicAdd(&cursor[d4.z], 1)] = s4.z;
        if (d4.w >= lo && d4.w < hi) col[atomicAdd(&cursor[d4.w], 1)] = s4.w;
    }
}

__global__ void scan1_kernel(const int* __restrict__ deg, int* __restrict__ row_ptr,
                             int* __restrict__ blksum, int n) {
    __shared__ int sh[256];
    int t = threadIdx.x;
    int i = blockIdx.x * 256 + t;
    int v = (i < n) ? deg[i] : 0;
    sh[t] = v;
    __syncthreads();
    for (int off = 1; off < 256; off <<= 1) {
        int add = (t >= off) ? sh[t - off] : 0;
        __syncthreads();
        sh[t] += add;
        __syncthreads();
    }
    int incl = sh[t];
    if (i < n) row_ptr[i] = incl - v;
    if (t == 255) blksum[blockIdx.x] = incl;
}

// one-block exclusive scan of block sums; also zeroes row n of hA/hB
__global__ void scan2_kernel(int* __restrict__ blksum, int nblk,
                             float* __restrict__ hA, float* __restrict__ hB) {
    __shared__ int sh[256];
    int t = threadIdx.x;
    if (t < HID) {
        hA[(size_t)N_NODES * HID + t] = 0.f;
        hB[(size_t)N_NODES * HID + t] = 0.f;
    }
    int v = (t < nblk) ? blksum[t] : 0;
    sh[t] = v;
    __syncthreads();
    for (int off = 1; off < 256; off <<= 1) {
        int add = (t >= off) ? sh[t - off] : 0;
        __syncthreads();
        sh[t] += add;
        __syncthreads();
    }
    if (t < nblk) blksum[t] = sh[t] - v;
}

__global__ void scan3_kernel(int* __restrict__ row_ptr, const int* __restrict__ blksum,
                             int* __restrict__ cursor, int n, int nE) {
    int i = blockIdx.x * 256 + threadIdx.x;
    if (i < n) {
        int r = row_ptr[i] + blksum[i >> 8];
        row_ptr[i] = r;
        cursor[i] = r;
    }
    if (i == 0) row_ptr[n] = nE;
}

// ---------------- fc_init: h0 = relu(features @ fc_w + fc_b) ----------------

#define FT_PITCH 132
#define FCNT 64

__global__ __launch_bounds__(256) void fc_init_kernel(
        const float* __restrict__ feat, const float* __restrict__ W,
        const float* __restrict__ bias, float* __restrict__ h, int n) {
    __shared__ float Wl[IN_DIM * HID];      // 32 KB
    __shared__ float ft[FCNT * FT_PITCH];   // 33 KB

    int base = blockIdx.x * FCNT;
    for (int i = threadIdx.x; i < IN_DIM * HID / 4; i += 256)
        *reinterpret_cast<v4f*>(&Wl[i * 4]) = *reinterpret_cast<const v4f*>(&W[i * 4]);
    {
        int f4 = threadIdx.x & 31;
        int r0 = threadIdx.x >> 5;
        for (int p = 0; p < 8; ++p) {
            int r = p * 8 + r0;
            int node = base + r;
            v4f v = {0.f, 0.f, 0.f, 0.f};
            if (node < n) v = *reinterpret_cast<const v4f*>(&feat[(size_t)node * IN_DIM + f4 * 4]);
            *reinterpret_cast<v4f*>(&ft[r * FT_PITCH + f4 * 4]) = v;
        }
    }
    __syncthreads();

    int tx = threadIdx.x & 15;
    int ty = threadIdx.x >> 4;
    v4f acc[4];
    v4f b4 = *reinterpret_cast<const v4f*>(&bias[tx * 4]);
    acc[0] = b4; acc[1] = b4; acc[2] = b4; acc[3] = b4;

#pragma unroll 16
    for (int k = 0; k < IN_DIM; ++k) {
        v4f w4 = *reinterpret_cast<const v4f*>(&Wl[k * HID + tx * 4]);
        float a0 = ft[(ty * 4 + 0) * FT_PITCH + k];
        float a1 = ft[(ty * 4 + 1) * FT_PITCH + k];
        float a2 = ft[(ty * 4 + 2) * FT_PITCH + k];
        float a3 = ft[(ty * 4 + 3) * FT_PITCH + k];
        acc[0] += a0 * w4;
        acc[1] += a1 * w4;
        acc[2] += a2 * w4;
        acc[3] += a3 * w4;
    }
#pragma unroll
    for (int i = 0; i < 4; ++i) {
        int node = base + ty * 4 + i;
        if (node < n) {
            v4f o;
            o[0] = fmaxf(acc[i][0], 0.f);
            o[1] = fmaxf(acc[i][1], 0.f);
            o[2] = fmaxf(acc[i][2], 0.f);
            o[3] = fmaxf(acc[i][3], 0.f);
            *reinterpret_cast<v4f*>(&h[(size_t)node * HID + tx * 4]) = o;
        }
    }
}

// ---------------- fused GIN layer (512 threads, NT=64) — round-4 shape ----
// Phase A: 8 waves x 8 nodes; 4 edges per load instruction (lane group g
// owns edge j*4+g, feature quad (lane&15)*4). Tail lanes carry index n
// (zero row), so the __shfl is UNCONDITIONAL -> convergent -> all source
// lanes active (divergent shfl reads 0 from inactive lanes).
// Phase B: 64x64x64 GEMM, 2 nodes x 4 outputs per thread, W in LDS.

__global__ __launch_bounds__(512) void gin_layer_kernel(
        const float* __restrict__ h_in, const int* __restrict__ row_ptr,
        const int* __restrict__ col, const float* __restrict__ W,
        const float* __restrict__ bias, const float* __restrict__ eps_arr, int layer,
        float* __restrict__ h_out, int n) {
    __shared__ float Wl[HID * HID];         // 16 KB
    __shared__ float rst[NT * RST_PITCH];   // 17 KB

    for (int i = threadIdx.x; i < HID * HID / 4; i += 512)
        *reinterpret_cast<v4f*>(&Wl[i * 4]) = *reinterpret_cast<const v4f*>(&W[i * 4]);

    int wid = threadIdx.x >> 6, lane = threadIdx.x & 63;
    int g = lane >> 4;          // edge subgroup 0..3
    int fo = (lane & 15) * 4;   // feature quad offset
    int base = blockIdx.x * NT;
    float eps1 = 1.f + eps_arr[layer];

    // phase A: gather-mean, 8 nodes per wave
    for (int t = 0; t < 8; ++t) {
        int r = wid * 8 + t;
        int node = base + r;
        if (node < n) {
            int s0 = row_ptr[node], s1 = row_ptr[node + 1];
            v4f acc = {0.f, 0.f, 0.f, 0.f};
            for (int e0 = s0; e0 < s1; e0 += 64) {
                int cnt = s1 - e0; if (cnt > 64) cnt = 64;
                int myc = (lane < cnt) ? col[e0 + lane] : n;  // tail -> zero row
                int jmax = (cnt + 3) >> 2;
#pragma unroll 4
                for (int j = 0; j < jmax; ++j) {
                    int idx = j * 4 + g;                      // <= 63 always
                    int sn = __shfl(myc, idx);                // convergent
                    acc += *reinterpret_cast<const v4f*>(&h_in[(size_t)sn * HID + fo]);
                }
            }
#pragma unroll
            for (int c = 0; c < 4; ++c) acc[c] += __shfl_xor(acc[c], 16);
#pragma unroll
            for (int c = 0; c < 4; ++c) acc[c] += __shfl_xor(acc[c], 32);
            int d = s1 - s0;
            float sc = (d > 0) ? 1.f / (float)d : 0.f;
            if (lane < 16) {
                v4f self = *reinterpret_cast<const v4f*>(&h_in[(size_t)node * HID + fo]);
                v4f rv = eps1 * self + acc * sc;
                *reinterpret_cast<v4f*>(&rst[r * RST_PITCH + fo]) = rv;
            }
        }
    }
    __syncthreads();

    // phase B: out = relu(rst @ W + b)
    int tx = threadIdx.x & 15;   // output quad
    int ty = threadIdx.x >> 4;   // node pair 0..31
    v4f b4 = *reinterpret_cast<const v4f*>(&bias[tx * 4]);
    v4f acc0 = b4, acc1 = b4;

#pragma unroll 16
    for (int k = 0; k < HID; ++k) {
        v4f w4 = *reinterpret_cast<const v4f*>(&Wl[k * HID + tx * 4]);
        float a0 = rst[(ty * 2 + 0) * RST_PITCH + k];
        float a1 = rst[(ty * 2 + 1) * RST_PITCH + k];
        acc0 += a0 * w4;
        acc1 += a1 * w4;
    }
    {
        int node = base + ty * 2;
        if (node < n) {
            v4f o;
            o[0] = fmaxf(acc0[0], 0.f); o[1] = fmaxf(acc0[1], 0.f);
            o[2] = fmaxf(acc0[2], 0.f); o[3] = fmaxf(acc0[3], 0.f);
            *reinterpret_cast<v4f*>(&h_out[(size_t)node * HID + tx * 4]) = o;
        }
        node = base + ty * 2 + 1;
        if (node < n) {
            v4f o;
            o[0] = fmaxf(acc1[0], 0.f); o[1] = fmaxf(acc1[1], 0.f);
            o[2] = fmaxf(acc1[2], 0.f); o[3] = fmaxf(acc1[3], 0.f);
            *reinterpret_cast<v4f*>(&h_out[(size_t)node * HID + tx * 4]) = o;
        }
    }
}

// ---------------- launch ----------------

extern "C" void kernel_launch(void* const* d_in, const int* in_sizes, int n_in,
                              void* d_out, int out_size, void* d_ws, size_t ws_size,
                              hipStream_t stream) {
    const float* feat = (const float*)d_in[0];
    const int*   src  = (const int*)d_in[1];
    const int*   dst  = (const int*)d_in[2];
    const float* fc_w = (const float*)d_in[3];
    const float* fc_b = (const float*)d_in[4];
    const float* w0   = (const float*)d_in[5];
    const float* b0   = (const float*)d_in[6];
    const float* w1   = (const float*)d_in[7];
    const float* b1   = (const float*)d_in[8];
    const float* w2   = (const float*)d_in[9];
    const float* b2   = (const float*)d_in[10];
    const float* eps  = (const float*)d_in[11];
    float* out = (float*)d_out;

    char* ws = (char*)d_ws;
    size_t off = 0;
    auto alloc = [&](size_t bytes) {
        size_t o = off;
        off += (bytes + 255) & ~(size_t)255;
        return (void*)(ws + o);
    };
    int*   deg     = (int*)alloc((size_t)N_NODES * 4);
    int*   row_ptr = (int*)alloc((size_t)(N_NODES + 1) * 4);
    int*   cursor  = (int*)alloc((size_t)N_NODES * 4);
    int*   blksum  = (int*)alloc(256 * 4);
    int*   col     = (int*)alloc((size_t)N_EDGES * 4);
    float* hA      = (float*)alloc((size_t)(N_NODES + 1) * HID * 4);
    float* hB      = (float*)alloc((size_t)(N_NODES + 1) * HID * 4);

    const int nblkN = (N_NODES + 255) / 256;   // 196
    const int sweepBlocks = NXCD * 256;        // 2048: 8 ranges x 256 chunks

    hipMemsetAsync(deg, 0, (size_t)N_NODES * 4, stream);
    deg_sweep_kernel<<<sweepBlocks, 256, 0, stream>>>(dst, deg);
    scan1_kernel<<<nblkN, 256, 0, stream>>>(deg, row_ptr, blksum, N_NODES);
    scan2_kernel<<<1, 256, 0, stream>>>(blksum, nblkN, hA, hB);
    scan3_kernel<<<nblkN, 256, 0, stream>>>(row_ptr, blksum, cursor, N_NODES, N_EDGES);
    fill_sweep_kernel<<<sweepBlocks, 256, 0, stream>>>(src, dst, cursor, col);

    const int fcBlocks = (N_NODES + FCNT - 1) / FCNT;   // 782
    fc_init_kernel<<<fcBlocks, 256, 0, stream>>>(feat, fc_w, fc_b, hA, N_NODES);
    const int ginBlocks = (N_NODES + NT - 1) / NT;      // 782
    gin_layer_kernel<<<ginBlocks, 512, 0, stream>>>(hA, row_ptr, col, w0, b0, eps, 0, hB, N_NODES);
    gin_layer_kernel<<<ginBlocks, 512, 0, stream>>>(hB, row_ptr, col, w1, b1, eps, 1, hA, N_NODES);
    gin_layer_kernel<<<ginBlocks, 512, 0, stream>>>(hA, row_ptr, col, w2, b2, eps, 2, out, N_NODES);
}